// Round 17
// baseline (1533.198 us; speedup 1.0000x reference)
//
#include <hip/hip_runtime.h>

typedef __attribute__((ext_vector_type(8)))  short short8;
typedef __attribute__((ext_vector_type(4)))  float f32x4;
typedef __attribute__((ext_vector_type(16))) float f32x16;

#define L0    8192
#define LFIN  4612
#define PSKIP 3580   // L0 - LFIN

// 16-row swizzle: spreads row-strided b128 reads across banks (8-row left
// 4-way aliasing: 10.1M conflict cycles/dispatch; this form measured 2.49M).
#define SWZ(rr) (((rr) & 15) << 4)

__device__ __forceinline__ unsigned short f2bf(float f) {
  unsigned u = __builtin_bit_cast(unsigned, f);
  u += 0x7fffu + ((u >> 16) & 1u);          // RNE
  return (unsigned short)(u >> 16);
}
__device__ __forceinline__ float bf2f(unsigned short h) {
  return __builtin_bit_cast(float, (unsigned)h << 16);
}

// ---------------- weight conversion f32 -> bf16, FRAGMENT-MAJOR layouts ----------------
// Every MFMA A-fragment load in group_mfma becomes base + lane*16B: one 1KB burst.
// Wd2: [l][w 2b][half 1b][ks 4b][lane 6b][j 3b]   (k = ks*16 + hi*8 + j; k=tap*128+ci)
// Wr2: [l][w 2b][ks 3b][lane 6b][j 3b]
// Ws2: [l][w 2b][t 1b][ks 3b][lane 6b][j 3b]
__global__ __launch_bounds__(256) void wconv_kernel(
    const float* __restrict__ dw, const float* __restrict__ rw,
    const float* __restrict__ sw, const float* __restrict__ ew,
    const float* __restrict__ skb,
    unsigned short* __restrict__ Wd, unsigned short* __restrict__ Wr,
    unsigned short* __restrict__ Ws, unsigned short* __restrict__ We,
    float* __restrict__ SBS)
{
  int e = blockIdx.x * 256 + threadIdx.x;
  const int ND = 39*65536, NR = 39*16384, NS = 39*32768, NE = 16384;
  if (e < ND) {
    int l = e >> 16, idx = e & 65535;
    int j = idx & 7, lane = (idx >> 3) & 63, ks = (idx >> 9) & 15;
    int half = (idx >> 13) & 1, w = idx >> 14;
    int ln = lane & 31, hi = lane >> 5;
    int co = half*128 + 32*w + ln;
    int k  = ks*16 + hi*8 + j;
    int tap = k >> 7, ci = k & 127;
    Wd[e] = f2bf(dw[(((size_t)l*256 + co)*128 + ci)*2 + tap]);
  } else if ((e -= ND) < NR) {
    int l = e >> 14, idx = e & 16383;
    int j = idx & 7, lane = (idx >> 3) & 63, ks = (idx >> 9) & 7, w = idx >> 12;
    int ln = lane & 31, hi = lane >> 5;
    int co = 32*w + ln, k = ks*16 + hi*8 + j;
    Wr[e] = f2bf(rw[((size_t)l*128 + co)*128 + k]);
  } else if ((e -= NR) < NS) {
    int l = e >> 15, idx = e & 32767;
    int j = idx & 7, lane = (idx >> 3) & 63, ks = (idx >> 9) & 7;
    int t = (idx >> 12) & 1, w = idx >> 13;
    int ln = lane & 31, hi = lane >> 5;
    int co = 128*t + 32*w + ln, k = ks*16 + hi*8 + j;
    Ws[e] = f2bf(sw[((size_t)l*256 + co)*128 + k]);
  } else if ((e -= NS) < NE) {
    We[e] = f2bf(ew[e]);
  } else if ((e -= NE) < 256) {
    float s = 0.f;
    for (int i = 0; i < 39; ++i) s += skb[i*256 + e];
    SBS[e] = s;
  }
}

// ---------------- start: 1x1 conv 40 -> 128, position-major bf16 output ----------------
__global__ __launch_bounds__(256) void start_kernel(
    const float* __restrict__ x, const float* __restrict__ w,
    const float* __restrict__ b, unsigned short* __restrict__ H)
{
  __shared__ float xs[40][64];
  __shared__ float wl[128*41];
  const int tid = threadIdx.x;
  const int n = blockIdx.y;
  const int p0 = blockIdx.x * 64;

  for (int e = tid; e < 40*64; e += 256) {
    int ci = e >> 6, t = e & 63;
    xs[ci][t] = x[((size_t)n*40 + ci)*L0 + p0 + t];
  }
  for (int e = tid; e < 128*40; e += 256)
    wl[(e/40)*41 + (e%40)] = w[e];
  __syncthreads();

  const int c  = tid & 127;
  const int ph = tid >> 7;                 // 0..1
  const float bias = b[c];
  #pragma unroll 4
  for (int k = 0; k < 32; ++k) {
    int p = ph + 2*k;
    float acc = bias;
    #pragma unroll
    for (int ci = 0; ci < 40; ++ci)
      acc = fmaf(wl[c*41 + ci], xs[ci][p], acc);
    H[((size_t)n*L0 + p0 + p)*128 + c] = f2bf(acc);
  }
}

// ---------------- gate f/g -> bf16 into Gl row p ----------------
__device__ __forceinline__ void gate_write(char* Gl, const float* __restrict__ dbl,
    const f32x16& af, const f32x16& ag, int p, int w, int hi)
{
  #pragma unroll
  for (int q = 0; q < 4; ++q) {
    int rbase = 8*q + 4*hi;
    const float4 bf4 = *(const float4*)&dbl[32*w + rbase];
    const float4 bg4 = *(const float4*)&dbl[128 + 32*w + rbase];
    const float bfv[4] = {bf4.x, bf4.y, bf4.z, bf4.w};
    const float bgv[4] = {bg4.x, bg4.y, bg4.z, bg4.w};
    unsigned short gs[4];
    #pragma unroll
    for (int r = 0; r < 4; ++r) {
      float fv = af[4*q + r] + bfv[r];
      float gg = ag[4*q + r] + bgv[r];
      float th = 2.f * __builtin_amdgcn_rcpf(1.f + __expf(-2.f * fv)) - 1.f;
      float sg = __builtin_amdgcn_rcpf(1.f + __expf(-gg));
      gs[r] = f2bf(th * sg);
    }
    ushort4 gv; gv.x = gs[0]; gv.y = gs[1]; gv.z = gs[2]; gv.w = gs[3];
    int byte = ((p << 8) + ((32*w + rbase) << 1)) ^ SWZ(p);
    *(ushort4*)(Gl + byte) = gv;
  }
}

// ---------------- res writeback: racc + bias + residual -> Hl row sl ----------------
__device__ __forceinline__ void res_writeback(char* Hl, const float* __restrict__ rbl,
    const f32x16& racc, int sl, int w, int hi)
{
  #pragma unroll
  for (int q = 0; q < 4; ++q) {
    int co = 32*w + 8*q + 4*hi;
    const float4 rb4 = *(const float4*)&rbl[co];
    int hbyte = ((sl << 8) + (co << 1)) ^ SWZ(sl);
    ushort4 hv = *(const ushort4*)(Hl + hbyte);
    ushort4 hb;
    hb.x = f2bf(racc[4*q]   + rb4.x + bf2f(hv.x));
    hb.y = f2bf(racc[4*q+1] + rb4.y + bf2f(hv.y));
    hb.z = f2bf(racc[4*q+2] + rb4.z + bf2f(hv.z));
    hb.w = f2bf(racc[4*q+3] + rb4.w + bf2f(hv.w));
    *(ushort4*)(Hl + hbyte) = hb;
  }
}

// ---------------- fused group of NL dilated layers (dils = s*{1,2,4,8,16}) ----------
// Session-best structure (R11/R16: 207 us/group, VGPR 172, 2 blocks/CU): 64 own +
// 32 halo slots in LDS, 3 GEMM1 tiles with weights hoisted (2 coalesced 1KB loads
// -> 6 MFMAs per ks), fragment-major weights, 16-row LDS swizzle, persistent skip
// accumulators in 4 named f32x16 regs, one SK RMW per group.
// This round (final isolated probe): mirror u for odd batches -- doSkip-heavy
// blocks (u>=55 at s=1, 33% more MFMA) interleave with light ones per CU instead
// of clustering in the dispatch tail. Scalar-only remap at kernel entry; cannot
// perturb vector register allocation (VGPR must stay 172 -- revert criterion).
// Session lessons: no launch_bounds cap (R12: spill); no tile shrink (R4/R10);
// no prefetch/merge (R13); no code duplication (R15).
__global__ __launch_bounds__(256, 1) void group_mfma(
    const unsigned short* __restrict__ Hin, unsigned short* __restrict__ Hout,
    float* __restrict__ SK,
    const unsigned short* __restrict__ Wd, const float* __restrict__ dilb,
    const unsigned short* __restrict__ Wr, const float* __restrict__ resb,
    const unsigned short* __restrict__ Ws,
    int s, int NL, int i0, int accum, int writeH)
{
  __shared__ __align__(16) unsigned short Hl[96*128];   // 24 KiB, row 256B swizzled
  __shared__ __align__(16) unsigned short Gl[96*128];   // 24 KiB

  const int tid = threadIdx.x;
  const int lb = blockIdx.x;
  const int n = lb & 7;                 // batch -> XCD (H L2-resident per XCD)
  int u = lb >> 3;                      // 0..127
  if (n & 1) u = 127 - u;               // mirror: heavy/light blocks mix per CU
  const int r = (s == 1) ? 0 : (u & 31);
  const int t = (s == 1) ? u : (u >> 5);
  const int mbase = t*64 - 32;          // slot j -> m = mbase + j ; pos = r + s*m

  const int w = tid >> 6, lane = tid & 63;
  const int ln = lane & 31, hi = lane >> 5;
  const int l8 = lane * 8;              // fragment offset base (ushorts)

  const unsigned short* __restrict__ Hb = Hin + (size_t)n * L0 * 128;

  // ---- stage 96 slots from global H ----
  #pragma unroll
  for (int it = 0; it < 6; ++it) {
    int e = it*256 + tid;               // 96 rows x 16 threads
    int c8 = (e & 15) << 3;
    int j  = e >> 4;
    int gp = r + s * (mbase + j);
    if (gp < 0) gp = 0;                 // halo below valid region: bounded garbage, unused
    short8 v = *(const short8*)&Hb[(size_t)gp * 128 + c8];
    *(short8*)((char*)Hl + (((j << 8) + (c8 << 1)) ^ SWZ(j))) = v;
  }
  __syncthreads();

  const f32x16 fz16 = {0.f};
  f32x16 sk00 = fz16, sk01 = fz16, sk10 = fz16, sk11 = fz16;
  const bool doSkip = (r + s*(t*64 + 63)) >= PSKIP;

  #pragma unroll 1
  for (int l = 0; l < NL; ++l) {
    const int i = i0 + l;
    const int dil = 1 << l;             // dilation in slot space
    const unsigned short* __restrict__ Wdl = Wd + (size_t)l*65536;
    const float* dbl = dilb + l*256;

    // ---- GEMM1: weights hoisted across 3 tiles (2 coalesced loads -> 6 MFMAs/ks) ----
    const int r1_0 = ln,      r1_1 = 32 + ln,  r1_2 = 64 + ln;
    int rc_0 = r1_0 - dil; if (rc_0 < 0) rc_0 = 0;
    const int rc_1 = r1_1 - dil, rc_2 = r1_2 - dil;   // >= 0 always
    f32x16 af0 = fz16, af1 = fz16, af2 = fz16;
    f32x16 ag0 = fz16, ag1 = fz16, ag2 = fz16;
    #pragma unroll
    for (int ks = 0; ks < 16; ++ks) {
      int colb = (ks & 7)*32 + hi*16;
      short8 Af = *(const short8*)&Wdl[(((w*2 + 0)*16 + ks) << 9) + l8];
      short8 Ag = *(const short8*)&Wdl[(((w*2 + 1)*16 + ks) << 9) + l8];
      int row0 = (ks < 8) ? rc_0 : r1_0;
      int row1 = (ks < 8) ? rc_1 : r1_1;
      int row2 = (ks < 8) ? rc_2 : r1_2;
      short8 B0 = *(const short8*)((const char*)Hl + (((row0 << 8) + colb) ^ SWZ(row0)));
      short8 B1 = *(const short8*)((const char*)Hl + (((row1 << 8) + colb) ^ SWZ(row1)));
      short8 B2 = *(const short8*)((const char*)Hl + (((row2 << 8) + colb) ^ SWZ(row2)));
      af0 = __builtin_amdgcn_mfma_f32_32x32x16_bf16(Af, B0, af0, 0, 0, 0);
      ag0 = __builtin_amdgcn_mfma_f32_32x32x16_bf16(Ag, B0, ag0, 0, 0, 0);
      af1 = __builtin_amdgcn_mfma_f32_32x32x16_bf16(Af, B1, af1, 0, 0, 0);
      ag1 = __builtin_amdgcn_mfma_f32_32x32x16_bf16(Ag, B1, ag1, 0, 0, 0);
      af2 = __builtin_amdgcn_mfma_f32_32x32x16_bf16(Af, B2, af2, 0, 0, 0);
      ag2 = __builtin_amdgcn_mfma_f32_32x32x16_bf16(Ag, B2, ag2, 0, 0, 0);
    }
    gate_write((char*)Gl, dbl, af0, ag0, r1_0, w, hi);
    gate_write((char*)Gl, dbl, af1, ag1, r1_1, w, hi);
    gate_write((char*)Gl, dbl, af2, ag2, r1_2, w, hi);
    __syncthreads();                    // Gl complete; all Hl reads of GEMM1 done

    // ---- skip GEMM on own tiles (slots 32..95) -> persistent named sk regs ----
    if (doSkip) {
      const unsigned short* __restrict__ Wsl = Ws + (size_t)l*32768;
      const int rB0 = 32 + ln, rB1 = 64 + ln;
      #pragma unroll
      for (int ks = 0; ks < 8; ++ks) {
        int colb = ks*32 + hi*16;
        short8 A0 = *(const short8*)&Wsl[(((w*2 + 0)*8 + ks) << 9) + l8];
        short8 A1 = *(const short8*)&Wsl[(((w*2 + 1)*8 + ks) << 9) + l8];
        short8 B0 = *(const short8*)((const char*)Gl + (((rB0 << 8) + colb) ^ SWZ(rB0)));
        short8 B1 = *(const short8*)((const char*)Gl + (((rB1 << 8) + colb) ^ SWZ(rB1)));
        sk00 = __builtin_amdgcn_mfma_f32_32x32x16_bf16(A0, B0, sk00, 0, 0, 0);
        sk01 = __builtin_amdgcn_mfma_f32_32x32x16_bf16(A0, B1, sk01, 0, 0, 0);
        sk10 = __builtin_amdgcn_mfma_f32_32x32x16_bf16(A1, B0, sk10, 0, 0, 0);
        sk11 = __builtin_amdgcn_mfma_f32_32x32x16_bf16(A1, B1, sk11, 0, 0, 0);
      }
    }

    // ---- res GEMM: weights hoisted across 3 tiles; update Hl in place ----
    if (i < 38) {
      const unsigned short* __restrict__ Wrl = Wr + (size_t)l*16384;
      const float* rbl = resb + l*128;
      f32x16 rk0 = fz16, rk1 = fz16, rk2 = fz16;
      #pragma unroll
      for (int ks = 0; ks < 8; ++ks) {
        int colb = ks*32 + hi*16;
        short8 A = *(const short8*)&Wrl[((w*8 + ks) << 9) + l8];
        short8 B0 = *(const short8*)((const char*)Gl + (((r1_0 << 8) + colb) ^ SWZ(r1_0)));
        short8 B1 = *(const short8*)((const char*)Gl + (((r1_1 << 8) + colb) ^ SWZ(r1_1)));
        short8 B2 = *(const short8*)((const char*)Gl + (((r1_2 << 8) + colb) ^ SWZ(r1_2)));
        rk0 = __builtin_amdgcn_mfma_f32_32x32x16_bf16(A, B0, rk0, 0, 0, 0);
        rk1 = __builtin_amdgcn_mfma_f32_32x32x16_bf16(A, B1, rk1, 0, 0, 0);
        rk2 = __builtin_amdgcn_mfma_f32_32x32x16_bf16(A, B2, rk2, 0, 0, 0);
      }
      if (l < NL-1)                     // halo tile not needed after last sub-layer
        res_writeback((char*)Hl, rbl, rk0, r1_0, w, hi);
      res_writeback((char*)Hl, rbl, rk1, r1_1, w, hi);
      res_writeback((char*)Hl, rbl, rk2, r1_2, w, hi);
    }
    __syncthreads();                    // Hl ready for next sub-layer; Gl reads done
  }

  // ---- write own 64 slots of final H to global (not needed after last group) ----
  if (writeH) {
    unsigned short* __restrict__ Ho = Hout + (size_t)n * L0 * 128;
    #pragma unroll
    for (int it = 0; it < 4; ++it) {
      int e = it*256 + tid;             // 64 rows x 16 threads
      int c8 = (e & 15) << 3;
      int j  = 32 + (e >> 4);
      int gp = r + s * (mbase + j);     // in [0, 8191] for own slots
      short8 v = *(const short8*)((const char*)Hl +
                   (((j << 8) + (c8 << 1)) ^ SWZ(j)));
      *(short8*)&Ho[(size_t)gp * 128 + c8] = v;
    }
  }

  // ---- SK read-modify-write, once per group ----
  if (doSkip) {
    float* SKn = SK + (size_t)n * LFIN * 256;
    #pragma unroll
    for (int nb = 0; nb < 2; ++nb) {
      int sl = 32 + nb*32 + ln;
      int p = r + s * (mbase + sl);
      if (p >= PSKIP) {
        int pi = p - PSKIP;
        #pragma unroll
        for (int q = 0; q < 4; ++q) {
          const f32x16& a0 = nb ? sk01 : sk00;
          const f32x16& a1 = nb ? sk11 : sk10;
          {
            int co = 32*w + 8*q + 4*hi;
            float* dst = &SKn[(size_t)pi * 256 + co];
            float4 v = make_float4(a0[4*q], a0[4*q+1], a0[4*q+2], a0[4*q+3]);
            if (accum) {
              float4 o = *(const float4*)dst;
              v.x += o.x; v.y += o.y; v.z += o.z; v.w += o.w;
            }
            *(float4*)dst = v;
          }
          {
            int co = 32*w + 128 + 8*q + 4*hi;
            float* dst = &SKn[(size_t)pi * 256 + co];
            float4 v = make_float4(a1[4*q], a1[4*q+1], a1[4*q+2], a1[4*q+3]);
            if (accum) {
              float4 o = *(const float4*)dst;
              v.x += o.x; v.y += o.y; v.z += o.z; v.w += o.w;
            }
            *(float4*)dst = v;
          }
        }
      }
    }
  }
}

// ---------------- end: relu(skip + total skip-bias) + 1x1 conv 256 -> 64 ----------------
__global__ __launch_bounds__(256) void end_mfma(
    const float* __restrict__ SK, const unsigned short* __restrict__ We,
    const float* __restrict__ SBS, const float* __restrict__ eb,
    float* __restrict__ out)
{
  __shared__ unsigned short sl[64*256];
  const int tid = threadIdx.x;
  const int n = blockIdx.y;
  const int p0 = blockIdx.x * 64;
  const float* __restrict__ SKn = SK + (size_t)n * LFIN * 256;

  #pragma unroll
  for (int it = 0; it < 16; ++it) {
    int e = it * 256 + tid;
    int c4 = (e & 63) << 2;
    int p  = e >> 6;
    int gp = p0 + p; if (gp > LFIN - 1) gp = LFIN - 1;
    float4 v = *(const float4*)&SKn[(size_t)gp * 256 + c4];
    float4 s4 = *(const float4*)&SBS[c4];
    ushort4 h;
    h.x = f2bf(fmaxf(v.x + s4.x, 0.f)); h.y = f2bf(fmaxf(v.y + s4.y, 0.f));
    h.z = f2bf(fmaxf(v.z + s4.z, 0.f)); h.w = f2bf(fmaxf(v.w + s4.w, 0.f));
    int byte = ((p << 9) + (c4 << 1)) ^ ((p & 7) << 4);
    *(ushort4*)((char*)sl + byte) = h;
  }
  __syncthreads();

  const int w  = tid >> 6, lane = tid & 63;
  const int lr = lane & 15, lg = lane >> 4;
  const f32x4 fz = {0.f, 0.f, 0.f, 0.f};
  f32x4 acc[4] = {fz, fz, fz, fz};

  #pragma unroll
  for (int ks = 0; ks < 8; ++ks) {
    short8 A = *(const short8*)&We[(size_t)(16*w + lr) * 256 + ks*32 + lg*8];
    #pragma unroll
    for (int nb = 0; nb < 4; ++nb) {
      int p = nb * 16 + lr;
      int byte = ((p << 9) + ((ks*32 + lg*8) << 1)) ^ ((p & 7) << 4);
      short8 B = *(const short8*)((const char*)sl + byte);
      acc[nb] = __builtin_amdgcn_mfma_f32_16x16x32_bf16(A, B, acc[nb], 0, 0, 0);
    }
  }
  #pragma unroll
  for (int nb = 0; nb < 4; ++nb) {
    int p = p0 + nb*16 + lr;
    if (p < LFIN) {
      #pragma unroll
      for (int r = 0; r < 4; ++r) {
        int co = 16*w + lg*4 + r;
        out[((size_t)n*64 + co) * LFIN + p] = acc[nb][r] + eb[co];
      }
    }
  }
}

// ---------------- host ----------------
extern "C" void kernel_launch(void* const* d_in, const int* in_sizes, int n_in,
                              void* d_out, int out_size, void* d_ws, size_t ws_size,
                              hipStream_t stream)
{
  const float* x      = (const float*)d_in[0];
  const float* startw = (const float*)d_in[1];
  const float* startb = (const float*)d_in[2];
  const float* dilw   = (const float*)d_in[3];
  const float* dilb   = (const float*)d_in[4];
  const float* resw   = (const float*)d_in[5];
  const float* resb   = (const float*)d_in[6];
  const float* skipw  = (const float*)d_in[7];
  const float* skipb  = (const float*)d_in[8];
  const float* endw   = (const float*)d_in[9];
  const float* endb   = (const float*)d_in[10];

  unsigned short* H0 = (unsigned short*)d_ws;       // [8][8192][128] bf16 pos-major
  unsigned short* H1 = H0 + (size_t)8*L0*128;
  float* SK = (float*)(H1 + (size_t)8*L0*128);      // [8][4612][256] f32 pos-major
  unsigned short* Wd = (unsigned short*)(SK + (size_t)8*LFIN*256);
  unsigned short* Wr = Wd + (size_t)39*65536;
  unsigned short* Ws = Wr + (size_t)39*16384;
  unsigned short* We = Ws + (size_t)39*32768;
  float* SBS = (float*)(We + 16384);

  const int total = 39*65536 + 39*16384 + 39*32768 + 16384 + 256;
  wconv_kernel<<<(total + 255)/256, 256, 0, stream>>>(dilw, resw, skipw, endw, skipb,
                                                      Wd, Wr, Ws, We, SBS);
  start_kernel<<<dim3(L0/64, 8), 256, 0, stream>>>(x, startw, startb, H0);

  // groups: 5 layers with dils s*{1,2,4,8,16} (last group: 4 layers)
  static const int GI0[8] = {0, 5, 10, 15, 20, 25, 30, 35};
  static const int GNL[8] = {5, 5, 5, 5, 5, 5, 5, 4};
  static const int GS [8] = {1, 32, 1, 32, 1, 32, 1, 32};

  unsigned short* bufs[2] = {H0, H1};
  for (int g = 0; g < 8; ++g) {
    int i0 = GI0[g];
    group_mfma<<<dim3(1024), 256, 0, stream>>>(
        bufs[g & 1], bufs[(g & 1) ^ 1], SK,
        Wd + (size_t)i0*65536, dilb + (size_t)i0*256,
        Wr + (size_t)i0*16384, resb + (size_t)i0*128,
        Ws + (size_t)i0*32768,
        GS[g], GNL[g], i0, g ? 1 : 0, (g < 7) ? 1 : 0);
  }

  end_mfma<<<dim3((LFIN + 63)/64, 8), 256, 0, stream>>>(SK, We, SBS, endb, (float*)d_out);
}

// Round 18
// 1403.144 us; speedup vs baseline: 1.0927x; 1.0927x over previous
//
#include <hip/hip_runtime.h>

typedef __attribute__((ext_vector_type(8)))  short short8;
typedef __attribute__((ext_vector_type(4)))  float f32x4;
typedef __attribute__((ext_vector_type(16))) float f32x16;

#define L0    8192
#define LFIN  4612
#define PSKIP 3580   // L0 - LFIN

// 16-row swizzle: spreads row-strided b128 reads across banks (8-row left
// 4-way aliasing: 10.1M conflict cycles/dispatch; this form measured 2.49M).
#define SWZ(rr) (((rr) & 15) << 4)

__device__ __forceinline__ unsigned short f2bf(float f) {
  unsigned u = __builtin_bit_cast(unsigned, f);
  u += 0x7fffu + ((u >> 16) & 1u);          // RNE
  return (unsigned short)(u >> 16);
}
__device__ __forceinline__ float bf2f(unsigned short h) {
  return __builtin_bit_cast(float, (unsigned)h << 16);
}

// ---------------- weight conversion f32 -> bf16, FRAGMENT-MAJOR layouts ----------------
// Every MFMA A-fragment load in group_mfma becomes base + lane*16B: one 1KB burst.
// Wd2: [l][w 2b][half 1b][ks 4b][lane 6b][j 3b]   (k = ks*16 + hi*8 + j; k=tap*128+ci)
// Wr2: [l][w 2b][ks 3b][lane 6b][j 3b]
// Ws2: [l][w 2b][t 1b][ks 3b][lane 6b][j 3b]
__global__ __launch_bounds__(256) void wconv_kernel(
    const float* __restrict__ dw, const float* __restrict__ rw,
    const float* __restrict__ sw, const float* __restrict__ ew,
    const float* __restrict__ skb,
    unsigned short* __restrict__ Wd, unsigned short* __restrict__ Wr,
    unsigned short* __restrict__ Ws, unsigned short* __restrict__ We,
    float* __restrict__ SBS)
{
  int e = blockIdx.x * 256 + threadIdx.x;
  const int ND = 39*65536, NR = 39*16384, NS = 39*32768, NE = 16384;
  if (e < ND) {
    int l = e >> 16, idx = e & 65535;
    int j = idx & 7, lane = (idx >> 3) & 63, ks = (idx >> 9) & 15;
    int half = (idx >> 13) & 1, w = idx >> 14;
    int ln = lane & 31, hi = lane >> 5;
    int co = half*128 + 32*w + ln;
    int k  = ks*16 + hi*8 + j;
    int tap = k >> 7, ci = k & 127;
    Wd[e] = f2bf(dw[(((size_t)l*256 + co)*128 + ci)*2 + tap]);
  } else if ((e -= ND) < NR) {
    int l = e >> 14, idx = e & 16383;
    int j = idx & 7, lane = (idx >> 3) & 63, ks = (idx >> 9) & 7, w = idx >> 12;
    int ln = lane & 31, hi = lane >> 5;
    int co = 32*w + ln, k = ks*16 + hi*8 + j;
    Wr[e] = f2bf(rw[((size_t)l*128 + co)*128 + k]);
  } else if ((e -= NR) < NS) {
    int l = e >> 15, idx = e & 32767;
    int j = idx & 7, lane = (idx >> 3) & 63, ks = (idx >> 9) & 7;
    int t = (idx >> 12) & 1, w = idx >> 13;
    int ln = lane & 31, hi = lane >> 5;
    int co = 128*t + 32*w + ln, k = ks*16 + hi*8 + j;
    Ws[e] = f2bf(sw[((size_t)l*256 + co)*128 + k]);
  } else if ((e -= NS) < NE) {
    We[e] = f2bf(ew[e]);
  } else if ((e -= NE) < 256) {
    float s = 0.f;
    for (int i = 0; i < 39; ++i) s += skb[i*256 + e];
    SBS[e] = s;
  }
}

// ---------------- start: 1x1 conv 40 -> 128, position-major bf16 output ----------------
__global__ __launch_bounds__(256) void start_kernel(
    const float* __restrict__ x, const float* __restrict__ w,
    const float* __restrict__ b, unsigned short* __restrict__ H)
{
  __shared__ float xs[40][64];
  __shared__ float wl[128*41];
  const int tid = threadIdx.x;
  const int n = blockIdx.y;
  const int p0 = blockIdx.x * 64;

  for (int e = tid; e < 40*64; e += 256) {
    int ci = e >> 6, t = e & 63;
    xs[ci][t] = x[((size_t)n*40 + ci)*L0 + p0 + t];
  }
  for (int e = tid; e < 128*40; e += 256)
    wl[(e/40)*41 + (e%40)] = w[e];
  __syncthreads();

  const int c  = tid & 127;
  const int ph = tid >> 7;                 // 0..1
  const float bias = b[c];
  #pragma unroll 4
  for (int k = 0; k < 32; ++k) {
    int p = ph + 2*k;
    float acc = bias;
    #pragma unroll
    for (int ci = 0; ci < 40; ++ci)
      acc = fmaf(wl[c*41 + ci], xs[ci][p], acc);
    H[((size_t)n*L0 + p0 + p)*128 + c] = f2bf(acc);
  }
}

// ---------------- gate f/g -> bf16 into Gl row p ----------------
__device__ __forceinline__ void gate_write(char* Gl, const float* __restrict__ dbl,
    const f32x16& af, const f32x16& ag, int p, int w, int hi)
{
  #pragma unroll
  for (int q = 0; q < 4; ++q) {
    int rbase = 8*q + 4*hi;
    const float4 bf4 = *(const float4*)&dbl[32*w + rbase];
    const float4 bg4 = *(const float4*)&dbl[128 + 32*w + rbase];
    const float bfv[4] = {bf4.x, bf4.y, bf4.z, bf4.w};
    const float bgv[4] = {bg4.x, bg4.y, bg4.z, bg4.w};
    unsigned short gs[4];
    #pragma unroll
    for (int r = 0; r < 4; ++r) {
      float fv = af[4*q + r] + bfv[r];
      float gg = ag[4*q + r] + bgv[r];
      float th = 2.f * __builtin_amdgcn_rcpf(1.f + __expf(-2.f * fv)) - 1.f;
      float sg = __builtin_amdgcn_rcpf(1.f + __expf(-gg));
      gs[r] = f2bf(th * sg);
    }
    ushort4 gv; gv.x = gs[0]; gv.y = gs[1]; gv.z = gs[2]; gv.w = gs[3];
    int byte = ((p << 8) + ((32*w + rbase) << 1)) ^ SWZ(p);
    *(ushort4*)(Gl + byte) = gv;
  }
}

// ---------------- res writeback: racc + bias + residual -> Hl row sl ----------------
__device__ __forceinline__ void res_writeback(char* Hl, const float* __restrict__ rbl,
    const f32x16& racc, int sl, int w, int hi)
{
  #pragma unroll
  for (int q = 0; q < 4; ++q) {
    int co = 32*w + 8*q + 4*hi;
    const float4 rb4 = *(const float4*)&rbl[co];
    int hbyte = ((sl << 8) + (co << 1)) ^ SWZ(sl);
    ushort4 hv = *(const ushort4*)(Hl + hbyte);
    ushort4 hb;
    hb.x = f2bf(racc[4*q]   + rb4.x + bf2f(hv.x));
    hb.y = f2bf(racc[4*q+1] + rb4.y + bf2f(hv.y));
    hb.z = f2bf(racc[4*q+2] + rb4.z + bf2f(hv.z));
    hb.w = f2bf(racc[4*q+3] + rb4.w + bf2f(hv.w));
    *(ushort4*)(Hl + hbyte) = hb;
  }
}

// ---------------- fused group of NL dilated layers (dils = s*{1,2,4,8,16}) ----------
// FINAL (session-best, verified twice: R11 1407us, R16 1405us): 64 own + 32 halo
// slots in LDS, 3 GEMM1 tiles with weights hoisted (2 coalesced 1KB loads -> 6
// MFMAs per ks), fragment-major weights, 16-row LDS swizzle, persistent skip
// accumulators in 4 named f32x16 regs, one SK RMW per group. VGPR 172, 2 blocks/CU.
// Session lessons (all measured): no launch_bounds cap (R12: cap -> spill, 4.5x
// traffic); no tile shrink (R4/R10: occupancy up, time up); no prefetch/merge
// (R13: +VGPR, -MfmaUtil); no code duplication (R15: peel -> VGPR 204, +23%);
// no u-mirror (R17: breaks halo L2 overlap between consecutive blocks, +8% FETCH).
// Sequential u order IS the L2 prefetch pattern -- do not remap it.
__global__ __launch_bounds__(256, 1) void group_mfma(
    const unsigned short* __restrict__ Hin, unsigned short* __restrict__ Hout,
    float* __restrict__ SK,
    const unsigned short* __restrict__ Wd, const float* __restrict__ dilb,
    const unsigned short* __restrict__ Wr, const float* __restrict__ resb,
    const unsigned short* __restrict__ Ws,
    int s, int NL, int i0, int accum, int writeH)
{
  __shared__ __align__(16) unsigned short Hl[96*128];   // 24 KiB, row 256B swizzled
  __shared__ __align__(16) unsigned short Gl[96*128];   // 24 KiB

  const int tid = threadIdx.x;
  const int lb = blockIdx.x;
  const int n = lb & 7;                 // batch -> XCD (H L2-resident per XCD)
  const int u = lb >> 3;                // 0..127
  const int r = (s == 1) ? 0 : (u & 31);
  const int t = (s == 1) ? u : (u >> 5);
  const int mbase = t*64 - 32;          // slot j -> m = mbase + j ; pos = r + s*m

  const int w = tid >> 6, lane = tid & 63;
  const int ln = lane & 31, hi = lane >> 5;
  const int l8 = lane * 8;              // fragment offset base (ushorts)

  const unsigned short* __restrict__ Hb = Hin + (size_t)n * L0 * 128;

  // ---- stage 96 slots from global H ----
  #pragma unroll
  for (int it = 0; it < 6; ++it) {
    int e = it*256 + tid;               // 96 rows x 16 threads
    int c8 = (e & 15) << 3;
    int j  = e >> 4;
    int gp = r + s * (mbase + j);
    if (gp < 0) gp = 0;                 // halo below valid region: bounded garbage, unused
    short8 v = *(const short8*)&Hb[(size_t)gp * 128 + c8];
    *(short8*)((char*)Hl + (((j << 8) + (c8 << 1)) ^ SWZ(j))) = v;
  }
  __syncthreads();

  const f32x16 fz16 = {0.f};
  f32x16 sk00 = fz16, sk01 = fz16, sk10 = fz16, sk11 = fz16;
  const bool doSkip = (r + s*(t*64 + 63)) >= PSKIP;

  #pragma unroll 1
  for (int l = 0; l < NL; ++l) {
    const int i = i0 + l;
    const int dil = 1 << l;             // dilation in slot space
    const unsigned short* __restrict__ Wdl = Wd + (size_t)l*65536;
    const float* dbl = dilb + l*256;

    // ---- GEMM1: weights hoisted across 3 tiles (2 coalesced loads -> 6 MFMAs/ks) ----
    const int r1_0 = ln,      r1_1 = 32 + ln,  r1_2 = 64 + ln;
    int rc_0 = r1_0 - dil; if (rc_0 < 0) rc_0 = 0;
    const int rc_1 = r1_1 - dil, rc_2 = r1_2 - dil;   // >= 0 always
    f32x16 af0 = fz16, af1 = fz16, af2 = fz16;
    f32x16 ag0 = fz16, ag1 = fz16, ag2 = fz16;
    #pragma unroll
    for (int ks = 0; ks < 16; ++ks) {
      int colb = (ks & 7)*32 + hi*16;
      short8 Af = *(const short8*)&Wdl[(((w*2 + 0)*16 + ks) << 9) + l8];
      short8 Ag = *(const short8*)&Wdl[(((w*2 + 1)*16 + ks) << 9) + l8];
      int row0 = (ks < 8) ? rc_0 : r1_0;
      int row1 = (ks < 8) ? rc_1 : r1_1;
      int row2 = (ks < 8) ? rc_2 : r1_2;
      short8 B0 = *(const short8*)((const char*)Hl + (((row0 << 8) + colb) ^ SWZ(row0)));
      short8 B1 = *(const short8*)((const char*)Hl + (((row1 << 8) + colb) ^ SWZ(row1)));
      short8 B2 = *(const short8*)((const char*)Hl + (((row2 << 8) + colb) ^ SWZ(row2)));
      af0 = __builtin_amdgcn_mfma_f32_32x32x16_bf16(Af, B0, af0, 0, 0, 0);
      ag0 = __builtin_amdgcn_mfma_f32_32x32x16_bf16(Ag, B0, ag0, 0, 0, 0);
      af1 = __builtin_amdgcn_mfma_f32_32x32x16_bf16(Af, B1, af1, 0, 0, 0);
      ag1 = __builtin_amdgcn_mfma_f32_32x32x16_bf16(Ag, B1, ag1, 0, 0, 0);
      af2 = __builtin_amdgcn_mfma_f32_32x32x16_bf16(Af, B2, af2, 0, 0, 0);
      ag2 = __builtin_amdgcn_mfma_f32_32x32x16_bf16(Ag, B2, ag2, 0, 0, 0);
    }
    gate_write((char*)Gl, dbl, af0, ag0, r1_0, w, hi);
    gate_write((char*)Gl, dbl, af1, ag1, r1_1, w, hi);
    gate_write((char*)Gl, dbl, af2, ag2, r1_2, w, hi);
    __syncthreads();                    // Gl complete; all Hl reads of GEMM1 done

    // ---- skip GEMM on own tiles (slots 32..95) -> persistent named sk regs ----
    if (doSkip) {
      const unsigned short* __restrict__ Wsl = Ws + (size_t)l*32768;
      const int rB0 = 32 + ln, rB1 = 64 + ln;
      #pragma unroll
      for (int ks = 0; ks < 8; ++ks) {
        int colb = ks*32 + hi*16;
        short8 A0 = *(const short8*)&Wsl[(((w*2 + 0)*8 + ks) << 9) + l8];
        short8 A1 = *(const short8*)&Wsl[(((w*2 + 1)*8 + ks) << 9) + l8];
        short8 B0 = *(const short8*)((const char*)Gl + (((rB0 << 8) + colb) ^ SWZ(rB0)));
        short8 B1 = *(const short8*)((const char*)Gl + (((rB1 << 8) + colb) ^ SWZ(rB1)));
        sk00 = __builtin_amdgcn_mfma_f32_32x32x16_bf16(A0, B0, sk00, 0, 0, 0);
        sk01 = __builtin_amdgcn_mfma_f32_32x32x16_bf16(A0, B1, sk01, 0, 0, 0);
        sk10 = __builtin_amdgcn_mfma_f32_32x32x16_bf16(A1, B0, sk10, 0, 0, 0);
        sk11 = __builtin_amdgcn_mfma_f32_32x32x16_bf16(A1, B1, sk11, 0, 0, 0);
      }
    }

    // ---- res GEMM: weights hoisted across 3 tiles; update Hl in place ----
    if (i < 38) {
      const unsigned short* __restrict__ Wrl = Wr + (size_t)l*16384;
      const float* rbl = resb + l*128;
      f32x16 rk0 = fz16, rk1 = fz16, rk2 = fz16;
      #pragma unroll
      for (int ks = 0; ks < 8; ++ks) {
        int colb = ks*32 + hi*16;
        short8 A = *(const short8*)&Wrl[((w*8 + ks) << 9) + l8];
        short8 B0 = *(const short8*)((const char*)Gl + (((r1_0 << 8) + colb) ^ SWZ(r1_0)));
        short8 B1 = *(const short8*)((const char*)Gl + (((r1_1 << 8) + colb) ^ SWZ(r1_1)));
        short8 B2 = *(const short8*)((const char*)Gl + (((r1_2 << 8) + colb) ^ SWZ(r1_2)));
        rk0 = __builtin_amdgcn_mfma_f32_32x32x16_bf16(A, B0, rk0, 0, 0, 0);
        rk1 = __builtin_amdgcn_mfma_f32_32x32x16_bf16(A, B1, rk1, 0, 0, 0);
        rk2 = __builtin_amdgcn_mfma_f32_32x32x16_bf16(A, B2, rk2, 0, 0, 0);
      }
      if (l < NL-1)                     // halo tile not needed after last sub-layer
        res_writeback((char*)Hl, rbl, rk0, r1_0, w, hi);
      res_writeback((char*)Hl, rbl, rk1, r1_1, w, hi);
      res_writeback((char*)Hl, rbl, rk2, r1_2, w, hi);
    }
    __syncthreads();                    // Hl ready for next sub-layer; Gl reads done
  }

  // ---- write own 64 slots of final H to global (not needed after last group) ----
  if (writeH) {
    unsigned short* __restrict__ Ho = Hout + (size_t)n * L0 * 128;
    #pragma unroll
    for (int it = 0; it < 4; ++it) {
      int e = it*256 + tid;             // 64 rows x 16 threads
      int c8 = (e & 15) << 3;
      int j  = 32 + (e >> 4);
      int gp = r + s * (mbase + j);     // in [0, 8191] for own slots
      short8 v = *(const short8*)((const char*)Hl +
                   (((j << 8) + (c8 << 1)) ^ SWZ(j)));
      *(short8*)&Ho[(size_t)gp * 128 + c8] = v;
    }
  }

  // ---- SK read-modify-write, once per group ----
  if (doSkip) {
    float* SKn = SK + (size_t)n * LFIN * 256;
    #pragma unroll
    for (int nb = 0; nb < 2; ++nb) {
      int sl = 32 + nb*32 + ln;
      int p = r + s * (mbase + sl);
      if (p >= PSKIP) {
        int pi = p - PSKIP;
        #pragma unroll
        for (int q = 0; q < 4; ++q) {
          const f32x16& a0 = nb ? sk01 : sk00;
          const f32x16& a1 = nb ? sk11 : sk10;
          {
            int co = 32*w + 8*q + 4*hi;
            float* dst = &SKn[(size_t)pi * 256 + co];
            float4 v = make_float4(a0[4*q], a0[4*q+1], a0[4*q+2], a0[4*q+3]);
            if (accum) {
              float4 o = *(const float4*)dst;
              v.x += o.x; v.y += o.y; v.z += o.z; v.w += o.w;
            }
            *(float4*)dst = v;
          }
          {
            int co = 32*w + 128 + 8*q + 4*hi;
            float* dst = &SKn[(size_t)pi * 256 + co];
            float4 v = make_float4(a1[4*q], a1[4*q+1], a1[4*q+2], a1[4*q+3]);
            if (accum) {
              float4 o = *(const float4*)dst;
              v.x += o.x; v.y += o.y; v.z += o.z; v.w += o.w;
            }
            *(float4*)dst = v;
          }
        }
      }
    }
  }
}

// ---------------- end: relu(skip + total skip-bias) + 1x1 conv 256 -> 64 ----------------
__global__ __launch_bounds__(256) void end_mfma(
    const float* __restrict__ SK, const unsigned short* __restrict__ We,
    const float* __restrict__ SBS, const float* __restrict__ eb,
    float* __restrict__ out)
{
  __shared__ unsigned short sl[64*256];
  const int tid = threadIdx.x;
  const int n = blockIdx.y;
  const int p0 = blockIdx.x * 64;
  const float* __restrict__ SKn = SK + (size_t)n * LFIN * 256;

  #pragma unroll
  for (int it = 0; it < 16; ++it) {
    int e = it * 256 + tid;
    int c4 = (e & 63) << 2;
    int p  = e >> 6;
    int gp = p0 + p; if (gp > LFIN - 1) gp = LFIN - 1;
    float4 v = *(const float4*)&SKn[(size_t)gp * 256 + c4];
    float4 s4 = *(const float4*)&SBS[c4];
    ushort4 h;
    h.x = f2bf(fmaxf(v.x + s4.x, 0.f)); h.y = f2bf(fmaxf(v.y + s4.y, 0.f));
    h.z = f2bf(fmaxf(v.z + s4.z, 0.f)); h.w = f2bf(fmaxf(v.w + s4.w, 0.f));
    int byte = ((p << 9) + (c4 << 1)) ^ ((p & 7) << 4);
    *(ushort4*)((char*)sl + byte) = h;
  }
  __syncthreads();

  const int w  = tid >> 6, lane = tid & 63;
  const int lr = lane & 15, lg = lane >> 4;
  const f32x4 fz = {0.f, 0.f, 0.f, 0.f};
  f32x4 acc[4] = {fz, fz, fz, fz};

  #pragma unroll
  for (int ks = 0; ks < 8; ++ks) {
    short8 A = *(const short8*)&We[(size_t)(16*w + lr) * 256 + ks*32 + lg*8];
    #pragma unroll
    for (int nb = 0; nb < 4; ++nb) {
      int p = nb * 16 + lr;
      int byte = ((p << 9) + ((ks*32 + lg*8) << 1)) ^ ((p & 7) << 4);
      short8 B = *(const short8*)((const char*)sl + byte);
      acc[nb] = __builtin_amdgcn_mfma_f32_16x16x32_bf16(A, B, acc[nb], 0, 0, 0);
    }
  }
  #pragma unroll
  for (int nb = 0; nb < 4; ++nb) {
    int p = p0 + nb*16 + lr;
    if (p < LFIN) {
      #pragma unroll
      for (int r = 0; r < 4; ++r) {
        int co = 16*w + lg*4 + r;
        out[((size_t)n*64 + co) * LFIN + p] = acc[nb][r] + eb[co];
      }
    }
  }
}

// ---------------- host ----------------
extern "C" void kernel_launch(void* const* d_in, const int* in_sizes, int n_in,
                              void* d_out, int out_size, void* d_ws, size_t ws_size,
                              hipStream_t stream)
{
  const float* x      = (const float*)d_in[0];
  const float* startw = (const float*)d_in[1];
  const float* startb = (const float*)d_in[2];
  const float* dilw   = (const float*)d_in[3];
  const float* dilb   = (const float*)d_in[4];
  const float* resw   = (const float*)d_in[5];
  const float* resb   = (const float*)d_in[6];
  const float* skipw  = (const float*)d_in[7];
  const float* skipb  = (const float*)d_in[8];
  const float* endw   = (const float*)d_in[9];
  const float* endb   = (const float*)d_in[10];

  unsigned short* H0 = (unsigned short*)d_ws;       // [8][8192][128] bf16 pos-major
  unsigned short* H1 = H0 + (size_t)8*L0*128;
  float* SK = (float*)(H1 + (size_t)8*L0*128);      // [8][4612][256] f32 pos-major
  unsigned short* Wd = (unsigned short*)(SK + (size_t)8*LFIN*256);
  unsigned short* Wr = Wd + (size_t)39*65536;
  unsigned short* Ws = Wr + (size_t)39*16384;
  unsigned short* We = Ws + (size_t)39*32768;
  float* SBS = (float*)(We + 16384);

  const int total = 39*65536 + 39*16384 + 39*32768 + 16384 + 256;
  wconv_kernel<<<(total + 255)/256, 256, 0, stream>>>(dilw, resw, skipw, endw, skipb,
                                                      Wd, Wr, Ws, We, SBS);
  start_kernel<<<dim3(L0/64, 8), 256, 0, stream>>>(x, startw, startb, H0);

  // groups: 5 layers with dils s*{1,2,4,8,16} (last group: 4 layers)
  static const int GI0[8] = {0, 5, 10, 15, 20, 25, 30, 35};
  static const int GNL[8] = {5, 5, 5, 5, 5, 5, 5, 4};
  static const int GS [8] = {1, 32, 1, 32, 1, 32, 1, 32};

  unsigned short* bufs[2] = {H0, H1};
  for (int g = 0; g < 8; ++g) {
    int i0 = GI0[g];
    group_mfma<<<dim3(1024), 256, 0, stream>>>(
        bufs[g & 1], bufs[(g & 1) ^ 1], SK,
        Wd + (size_t)i0*65536, dilb + (size_t)i0*256,
        Wr + (size_t)i0*16384, resb + (size_t)i0*128,
        Ws + (size_t)i0*32768,
        GS[g], GNL[g], i0, g ? 1 : 0, (g < 7) ? 1 : 0);
  }

  end_mfma<<<dim3((LFIN + 63)/64, 8), 256, 0, stream>>>(SK, We, SBS, endb, (float*)d_out);
}